// Round 1
// baseline (1140.197 us; speedup 1.0000x reference)
//
#include <hip/hip_runtime.h>
#include <hip/hip_bf16.h>

// EdgeMLP: out[e] = relu(relu(concat(h1[src],h1[dst],h2[src],h2[dst]) @ W0 + b0) @ W1 + b1) @ W2 + b2
// Strategy: bf16 MFMA (16x16x32), 64 edges per 256-thread block, gathered A-tile in
// swizzled LDS, weights pre-transposed to [N][K] bf16 in workspace.

typedef __attribute__((ext_vector_type(8))) __bf16 bf16x8;
typedef __attribute__((ext_vector_type(4))) __bf16 bf16x4;
typedef __attribute__((ext_vector_type(4))) float  floatx4;

__device__ inline floatx4 mfma16x16x32(bf16x8 a, bf16x8 b, floatx4 c) {
  return __builtin_amdgcn_mfma_f32_16x16x32_bf16(a, b, c, 0, 0, 0);
}

// ---- prep: f32 -> bf16 node feature tables ----
__global__ void cvt_nodes_kernel(const float* __restrict__ h1,
                                 const float* __restrict__ h2,
                                 __bf16* __restrict__ hb1,
                                 __bf16* __restrict__ hb2, int n4) {
  const int stride = gridDim.x * blockDim.x;
  for (int i = blockIdx.x * blockDim.x + threadIdx.x; i < 2 * n4; i += stride) {
    const bool second = i >= n4;
    const int j = second ? i - n4 : i;
    const float4 v = reinterpret_cast<const float4*>(second ? h2 : h1)[j];
    bf16x4 o;
    o[0] = (__bf16)v.x; o[1] = (__bf16)v.y; o[2] = (__bf16)v.z; o[3] = (__bf16)v.w;
    reinterpret_cast<bf16x4*>(second ? hb2 : hb1)[j] = o;
  }
}

// ---- prep: transpose weights to bf16 [N][K] ----
__global__ void cvt_w_kernel(const float* __restrict__ W0, const float* __restrict__ W1,
                             __bf16* __restrict__ W0T, __bf16* __restrict__ W1T) {
  const int t = blockIdx.x * 256 + threadIdx.x;
  if (t < 128 * 256) {                 // W0T[n][k] = W0[k][n], n<128, k<256
    const int n = t >> 8, k = t & 255;
    W0T[t] = (__bf16)W0[k * 128 + n];
  } else {                             // W1T[n][k] = W1[k][n], n<128, k<128
    const int t2 = t - 128 * 256;
    const int n = t2 >> 7, k = t2 & 127;
    W1T[t2] = (__bf16)W1[k * 128 + n];
  }
}

// ---- main kernel ----
template <bool BT>
__global__ __launch_bounds__(256, 3)
void edge_mlp_kernel(const void* __restrict__ t1, const void* __restrict__ t2,
                     const int* __restrict__ srcI, const int* __restrict__ dstI,
                     const __bf16* __restrict__ W0T, const float* __restrict__ b0,
                     const __bf16* __restrict__ W1T, const float* __restrict__ b1,
                     const float* __restrict__ W2, const float* __restrict__ b2,
                     float* __restrict__ out, int E) {
  // sA: [64 edges][256 feats] bf16, row stride 512 B, XOR-swizzled (G4)
  // sH: [64 edges][128 feats] bf16, row stride 256 B, XOR-swizzled
  __shared__ char sA[64 * 512];
  __shared__ char sH[64 * 256];

  const int tid = threadIdx.x;
  const int ebase = blockIdx.x * 64;

  { // stage A-tile: 4 threads per edge, one 64-feature segment each
    const int e = tid >> 2, s = tid & 3;   // s: 0=h1[src] 1=h1[dst] 2=h2[src] 3=h2[dst]
    const int ge = ebase + e;
    int idx = 0;
    if (ge < E) idx = (s & 1) ? dstI[ge] : srcI[ge];
    char* dp = sA + e * 512;
    const int swz = (e & 7) << 4;
    if (BT) {
      const bf16x8* row = reinterpret_cast<const bf16x8*>(
          reinterpret_cast<const __bf16*>(s < 2 ? t1 : t2) + (size_t)idx * 64);
#pragma unroll
      for (int i = 0; i < 8; ++i)
        *reinterpret_cast<bf16x8*>(dp + ((s * 128 + i * 16) ^ swz)) = row[i];
    } else {
      const float4* row = reinterpret_cast<const float4*>(
          reinterpret_cast<const float*>(s < 2 ? t1 : t2) + (size_t)idx * 64);
#pragma unroll
      for (int i = 0; i < 8; ++i) {
        const float4 x = row[2 * i], y = row[2 * i + 1];
        bf16x8 v;
        v[0] = (__bf16)x.x; v[1] = (__bf16)x.y; v[2] = (__bf16)x.z; v[3] = (__bf16)x.w;
        v[4] = (__bf16)y.x; v[5] = (__bf16)y.y; v[6] = (__bf16)y.z; v[7] = (__bf16)y.w;
        *reinterpret_cast<bf16x8*>(dp + ((s * 128 + i * 16) ^ swz)) = v;
      }
    }
  }
  __syncthreads();

  const int wave = tid >> 6;
  const int lane = tid & 63;
  const int l15 = lane & 15;
  const int hi = lane >> 4;
  const int mrow = wave * 16 + l15;  // A-fragment row (edge within tile) for this lane

  // per-lane column constants (col = nt*16 + l15)
  float b0c[8], b1c[8], w2c[8];
#pragma unroll
  for (int nt = 0; nt < 8; ++nt) {
    const int col = nt * 16 + l15;
    b0c[nt] = b0[col];
    b1c[nt] = b1[col];
    w2c[nt] = W2[col];
  }
  const float b2v = b2[0];

  // ---- layer 0: [64,256] x [256,128] ----
  floatx4 acc[8];
#pragma unroll
  for (int nt = 0; nt < 8; ++nt) acc[nt] = (floatx4)0.0f;
  {
    const char* aBase = sA + mrow * 512;
    const int aswz = (mrow & 7) << 4;
#pragma unroll
    for (int kk = 0; kk < 8; ++kk) {
      const bf16x8 a =
          *reinterpret_cast<const bf16x8*>(aBase + ((kk * 64 + hi * 16) ^ aswz));
#pragma unroll
      for (int nt = 0; nt < 8; ++nt) {
        const bf16x8 bf = *reinterpret_cast<const bf16x8*>(
            W0T + (nt * 16 + l15) * 256 + kk * 32 + hi * 8);
        acc[nt] = mfma16x16x32(a, bf, acc[nt]);
      }
    }
  }

  // bias + relu -> sH (wave-private 16-row slice, swizzled)
  {
#pragma unroll
    for (int nt = 0; nt < 8; ++nt) {
      const int col2 = (nt * 16 + l15) * 2;
#pragma unroll
      for (int r = 0; r < 4; ++r) {
        const int row = wave * 16 + hi * 4 + r;  // C/D layout: row=(lane>>4)*4+reg
        const float v = fmaxf(acc[nt][r] + b0c[nt], 0.0f);
        *reinterpret_cast<__bf16*>(sH + row * 256 + (col2 ^ ((row & 7) << 4))) =
            (__bf16)v;
      }
    }
  }
  __syncthreads();

  // ---- layer 1: [64,128] x [128,128] ----
  floatx4 acc2[8];
#pragma unroll
  for (int nt = 0; nt < 8; ++nt) acc2[nt] = (floatx4)0.0f;
  {
    const char* hB = sH + mrow * 256;
    const int hswz = (mrow & 7) << 4;
#pragma unroll
    for (int kk = 0; kk < 4; ++kk) {
      const bf16x8 a =
          *reinterpret_cast<const bf16x8*>(hB + ((kk * 64 + hi * 16) ^ hswz));
#pragma unroll
      for (int nt = 0; nt < 8; ++nt) {
        const bf16x8 bf = *reinterpret_cast<const bf16x8*>(
            W1T + (nt * 16 + l15) * 128 + kk * 32 + hi * 8);
        acc2[nt] = mfma16x16x32(a, bf, acc2[nt]);
      }
    }
  }

  // ---- layer 2: relu(.)·W2 + b2, reduce over 128 cols ----
  float s0 = 0.f, s1 = 0.f, s2 = 0.f, s3 = 0.f;
#pragma unroll
  for (int nt = 0; nt < 8; ++nt) {
    s0 += fmaxf(acc2[nt][0] + b1c[nt], 0.0f) * w2c[nt];
    s1 += fmaxf(acc2[nt][1] + b1c[nt], 0.0f) * w2c[nt];
    s2 += fmaxf(acc2[nt][2] + b1c[nt], 0.0f) * w2c[nt];
    s3 += fmaxf(acc2[nt][3] + b1c[nt], 0.0f) * w2c[nt];
  }
  // reduce over the 16 lanes sharing `hi` (masks 1,2,4,8 stay within the group)
#pragma unroll
  for (int m = 1; m < 16; m <<= 1) {
    s0 += __shfl_xor(s0, m);
    s1 += __shfl_xor(s1, m);
    s2 += __shfl_xor(s2, m);
    s3 += __shfl_xor(s3, m);
  }
  if (l15 < 4) {
    const int ge = ebase + wave * 16 + hi * 4 + l15;
    if (ge < E) {
      const float r = (l15 == 0) ? s0 : (l15 == 1) ? s1 : (l15 == 2) ? s2 : s3;
      out[ge] = r + b2v;
    }
  }
}

extern "C" void kernel_launch(void* const* d_in, const int* in_sizes, int n_in,
                              void* d_out, int out_size, void* d_ws, size_t ws_size,
                              hipStream_t stream) {
  const float* h1 = (const float*)d_in[0];
  const float* h2 = (const float*)d_in[1];
  const int* src = (const int*)d_in[2];
  const int* dst = (const int*)d_in[3];
  const float* W0 = (const float*)d_in[4];
  const float* b0 = (const float*)d_in[5];
  const float* W1 = (const float*)d_in[6];
  const float* b1 = (const float*)d_in[7];
  const float* W2 = (const float*)d_in[8];
  const float* b2 = (const float*)d_in[9];
  float* out = (float*)d_out;

  const int D = 64;
  const int nNodes = in_sizes[0] / D;
  const int E = in_sizes[2];

  char* ws = (char*)d_ws;
  __bf16* W0T = (__bf16*)(ws);             // 128*256*2 = 65536 B
  __bf16* W1T = (__bf16*)(ws + 65536);     // 128*128*2 = 32768 B
  __bf16* hb1 = (__bf16*)(ws + 98304);
  const size_t hbBytes = (size_t)nNodes * D * sizeof(__bf16);
  __bf16* hb2 = (__bf16*)(ws + 98304 + hbBytes);
  const bool useBT = ws_size >= 98304 + 2 * hbBytes;

  cvt_w_kernel<<<dim3(192), dim3(256), 0, stream>>>(W0, W1, W0T, W1T);

  const int tiles = (E + 63) / 64;
  if (useBT) {
    const int n4 = nNodes * D / 4;
    int blocks = (2 * n4 + 255) / 256;
    if (blocks > 2048) blocks = 2048;
    cvt_nodes_kernel<<<dim3(blocks), dim3(256), 0, stream>>>(h1, h2, hb1, hb2, n4);
    edge_mlp_kernel<true><<<dim3(tiles), dim3(256), 0, stream>>>(
        (const void*)hb1, (const void*)hb2, src, dst, W0T, b0, W1T, b1, W2, b2, out, E);
  } else {
    edge_mlp_kernel<false><<<dim3(tiles), dim3(256), 0, stream>>>(
        (const void*)h1, (const void*)h2, src, dst, W0T, b0, W1T, b1, W2, b2, out, E);
  }
}

// Round 2
// 267.491 us; speedup vs baseline: 4.2626x; 4.2626x over previous
//
#include <hip/hip_runtime.h>
#include <hip/hip_bf16.h>
#include <stdint.h>

// EdgeMLP: out[e] = relu(relu(concat(h1[src],h1[dst],h2[src],h2[dst]) @ W0 + b0) @ W1 + b1) @ W2 + b2
// Round 2: persistent blocks, register-resident weights (wave N-split),
// global_load_lds gather with both-sides XOR swizzle, double-buffered sA.

typedef __attribute__((ext_vector_type(8))) __bf16 bf16x8;
typedef __attribute__((ext_vector_type(4))) __bf16 bf16x4;
typedef __attribute__((ext_vector_type(4))) float  floatx4;

__device__ inline floatx4 mfma16x16x32(bf16x8 a, bf16x8 b, floatx4 c) {
  return __builtin_amdgcn_mfma_f32_16x16x32_bf16(a, b, c, 0, 0, 0);
}

__device__ inline void bar_lds() {
  asm volatile("s_waitcnt lgkmcnt(0)" ::: "memory");
  __builtin_amdgcn_s_barrier();
}

// ---- prep: f32 -> bf16 node feature tables ----
__global__ void cvt_nodes_kernel(const float* __restrict__ h1,
                                 const float* __restrict__ h2,
                                 __bf16* __restrict__ hb1,
                                 __bf16* __restrict__ hb2, int n4) {
  const int stride = gridDim.x * blockDim.x;
  for (int i = blockIdx.x * blockDim.x + threadIdx.x; i < 2 * n4; i += stride) {
    const bool second = i >= n4;
    const int j = second ? i - n4 : i;
    const float4 v = reinterpret_cast<const float4*>(second ? h2 : h1)[j];
    bf16x4 o;
    o[0] = (__bf16)v.x; o[1] = (__bf16)v.y; o[2] = (__bf16)v.z; o[3] = (__bf16)v.w;
    reinterpret_cast<bf16x4*>(second ? hb2 : hb1)[j] = o;
  }
}

// ---- prep: transpose weights to bf16 [N][K] ----
__global__ void cvt_w_kernel(const float* __restrict__ W0, const float* __restrict__ W1,
                             __bf16* __restrict__ W0T, __bf16* __restrict__ W1T) {
  const int t = blockIdx.x * 256 + threadIdx.x;
  if (t < 128 * 256) {                 // W0T[n][k] = W0[k][n]
    const int n = t >> 8, k = t & 255;
    W0T[t] = (__bf16)W0[k * 128 + n];
  } else {
    const int t2 = t - 128 * 256;      // W1T[n][k] = W1[k][n]
    const int n = t2 >> 7, k = t2 & 127;
    W1T[t2] = (__bf16)W1[k * 128 + n];
  }
}

// ---- main kernel ----
__global__ __launch_bounds__(256, 2)
void edge_mlp_kernel(const __bf16* __restrict__ hb1, const __bf16* __restrict__ hb2,
                     const int* __restrict__ srcI, const int* __restrict__ dstI,
                     const __bf16* __restrict__ W0T, const float* __restrict__ b0,
                     const __bf16* __restrict__ W1T, const float* __restrict__ b1,
                     const float* __restrict__ W2, const float* __restrict__ b2,
                     float* __restrict__ out, int E, int nTiles) {
  // sA: 2 x [64 edges][256 feats] bf16 (double buffer), row stride 512 B.
  // Physical layout linear (global_load_lds); logical chunk c stored at
  // phys c^(e&7); reads XOR the byte offset with (row&7)<<4.
  // sH: [64][128] bf16, row stride 256 B, same XOR swizzle.
  __shared__ char sA[2 * 64 * 512];
  __shared__ char sH[64 * 256];

  const int tid  = threadIdx.x;
  const int lane = tid & 63;
  const int l15  = lane & 15;
  const int hi   = lane >> 4;
  const int hi16 = hi * 16;
  const int wvU  = __builtin_amdgcn_readfirstlane(tid >> 6);  // wave id (uniform)
  const int wv16 = wvU * 16;
  const int wvByte = wvU * 8192;

  // gather role of this lane
  const int lhalf = lane >> 5;          // which of the 2 edges per issue
  const int sseg  = (lane >> 3) & 3;    // 0=h1[src] 1=h1[dst] 2=h2[src] 3=h2[dst]
  const int* idxTab = (sseg & 1) ? dstI : srcI;
  const __bf16* segBase = (sseg < 2) ? hb1 : hb2;

  // ---- per-wave register-resident weights (N-split: cols [32*wv, 32*wv+32)) ----
  const int col0 = (2 * wvU) * 16 + l15;
  const int col1 = col0 + 16;
  bf16x8 w0f[8][2];
  const bf16x8* w0p = reinterpret_cast<const bf16x8*>(W0T);
#pragma unroll
  for (int kk = 0; kk < 8; ++kk) {
    w0f[kk][0] = w0p[col0 * 32 + kk * 4 + hi];
    w0f[kk][1] = w0p[col1 * 32 + kk * 4 + hi];
  }
  bf16x8 w1f[4][2];
  const bf16x8* w1p = reinterpret_cast<const bf16x8*>(W1T);
#pragma unroll
  for (int kk = 0; kk < 4; ++kk) {
    w1f[kk][0] = w1p[col0 * 16 + kk * 4 + hi];
    w1f[kk][1] = w1p[col1 * 16 + kk * 4 + hi];
  }
  float b0c[2] = {b0[col0], b0[col1]};
  float b1c[2] = {b1[col0], b1[col1]};
  float w2c[2] = {W2[col0], W2[col1]};
  const float b2v = b2[0];

  const int tstride = gridDim.x;

  auto loadIdx = [&](int (&dst8)[8], int tt2) {
    const bool valid = tt2 < nTiles;
#pragma unroll
    for (int i = 0; i < 8; ++i) {
      const int eLoc = wv16 + i * 2 + lhalf;
      const int ge = tt2 * 64 + eLoc;
      dst8[i] = (valid && ge < E) ? idxTab[ge] : 0;
    }
  };

  auto issueGather = [&](int nb, const int (&idx8)[8]) {
#pragma unroll
    for (int i = 0; i < 8; ++i) {
      const int eLoc = wv16 + i * 2 + lhalf;
      const int c = (lane & 7) ^ (eLoc & 7);
      const __bf16* g = segBase + (size_t)idx8[i] * 64 + c * 8;
      char* l = sA + nb * 32768 + wvByte + i * 1024;  // + lane*16 added by HW
      __builtin_amdgcn_global_load_lds(
          (const __attribute__((address_space(1))) void*)g,
          (__attribute__((address_space(3))) void*)l, 16, 0, 0);
    }
  };

  // ---- prologue ----
  int tile0 = blockIdx.x;
  int idxA[8], idxB[8];
  loadIdx(idxA, tile0);
  issueGather(0, idxA);                 // gathers for first tile -> buf0
  loadIdx(idxB, tile0 + tstride);       // indices for tile+1
  int cur = 0;

  for (int tt = tile0; tt < nTiles; tt += tstride) {
    __syncthreads();  // drains vmcnt: buf[cur] ready; orders sH/sRed reuse

    // prefetch next tile's gathers and next-next indices
    if (tt + tstride < nTiles) issueGather(cur ^ 1, idxB);
    loadIdx(idxA, tt + 2 * tstride);

    const char* sAc = sA + cur * 32768;

    // ---- layer 0: [64,256] @ [256,128], this wave's 32 cols ----
    floatx4 acc[4][2];
#pragma unroll
    for (int mt = 0; mt < 4; ++mt) { acc[mt][0] = (floatx4)0.f; acc[mt][1] = (floatx4)0.f; }
#pragma unroll
    for (int kk = 0; kk < 8; ++kk) {
#pragma unroll
      for (int mt = 0; mt < 4; ++mt) {
        const int row = mt * 16 + l15;
        const bf16x8 a = *reinterpret_cast<const bf16x8*>(
            sAc + row * 512 + ((kk * 64 + hi16) ^ ((row & 7) << 4)));
        acc[mt][0] = mfma16x16x32(a, w0f[kk][0], acc[mt][0]);
        acc[mt][1] = mfma16x16x32(a, w0f[kk][1], acc[mt][1]);
      }
    }

    // bias + relu -> sH (swizzled row-major [64][128] bf16)
#pragma unroll
    for (int mt = 0; mt < 4; ++mt) {
#pragma unroll
      for (int nt = 0; nt < 2; ++nt) {
        const int col2 = (nt ? col1 : col0) * 2;
#pragma unroll
        for (int r = 0; r < 4; ++r) {
          const int row = mt * 16 + hi * 4 + r;
          const float v = fmaxf(acc[mt][nt][r] + b0c[nt], 0.0f);
          *reinterpret_cast<__bf16*>(sH + row * 256 + (col2 ^ ((row & 7) << 4))) =
              (__bf16)v;
        }
      }
    }
    bar_lds();  // B2: sH visible

    // ---- layer 1: [64,128] @ [128,128], this wave's 32 cols ----
    floatx4 acc2[4][2];
#pragma unroll
    for (int mt = 0; mt < 4; ++mt) { acc2[mt][0] = (floatx4)0.f; acc2[mt][1] = (floatx4)0.f; }
#pragma unroll
    for (int kk = 0; kk < 4; ++kk) {
#pragma unroll
      for (int mt = 0; mt < 4; ++mt) {
        const int row = mt * 16 + l15;
        const bf16x8 a = *reinterpret_cast<const bf16x8*>(
            sH + row * 256 + ((kk * 64 + hi16) ^ ((row & 7) << 4)));
        acc2[mt][0] = mfma16x16x32(a, w1f[kk][0], acc2[mt][0]);
        acc2[mt][1] = mfma16x16x32(a, w1f[kk][1], acc2[mt][1]);
      }
    }

    // ---- layer 2: partial dot over this wave's 32 cols, cross-wave reduce ----
    float* sRedF = (float*)sAc;  // overlay on consumed sA[cur] (layer0 done at B2)
#pragma unroll
    for (int mt = 0; mt < 4; ++mt) {
      float s0 = 0.f, s1 = 0.f, s2 = 0.f, s3 = 0.f;
#pragma unroll
      for (int nt = 0; nt < 2; ++nt) {
        s0 += fmaxf(acc2[mt][nt][0] + b1c[nt], 0.0f) * w2c[nt];
        s1 += fmaxf(acc2[mt][nt][1] + b1c[nt], 0.0f) * w2c[nt];
        s2 += fmaxf(acc2[mt][nt][2] + b1c[nt], 0.0f) * w2c[nt];
        s3 += fmaxf(acc2[mt][nt][3] + b1c[nt], 0.0f) * w2c[nt];
      }
#pragma unroll
      for (int m = 1; m < 16; m <<= 1) {
        s0 += __shfl_xor(s0, m);
        s1 += __shfl_xor(s1, m);
        s2 += __shfl_xor(s2, m);
        s3 += __shfl_xor(s3, m);
      }
      if (l15 < 4) {
        const float sv = (l15 == 0) ? s0 : (l15 == 1) ? s1 : (l15 == 2) ? s2 : s3;
        sRedF[wvU * 64 + mt * 16 + hi * 4 + l15] = sv;
      }
    }
    bar_lds();  // B3: partials visible

    if (tid < 64) {
      const int ge = tt * 64 + tid;
      if (ge < E) {
        out[ge] = sRedF[tid] + sRedF[64 + tid] + sRedF[128 + tid] +
                  sRedF[192 + tid] + b2v;
      }
    }

    // rotate prefetched indices
#pragma unroll
    for (int i = 0; i < 8; ++i) idxB[i] = idxA[i];
    cur ^= 1;
  }
}

// ---- correctness fallback (only if workspace too small for bf16 tables) ----
__global__ void edge_mlp_fallback(const float* __restrict__ h1, const float* __restrict__ h2,
                                  const int* __restrict__ src, const int* __restrict__ dst,
                                  const float* __restrict__ W0, const float* __restrict__ b0,
                                  const float* __restrict__ W1, const float* __restrict__ b1,
                                  const float* __restrict__ W2, const float* __restrict__ b2,
                                  float* __restrict__ out, int E) {
  __shared__ float sa[256];
  __shared__ float sh[128];
  __shared__ float sr[128];
  const int e = blockIdx.x;
  if (e >= E) return;
  const int t = threadIdx.x;  // 128 threads
  const int is = src[e], id = dst[e];
  if (t < 64) { sa[t] = h1[is * 64 + t]; sa[128 + t] = h2[is * 64 + t]; }
  else { const int u = t - 64; sa[64 + u] = h1[id * 64 + u]; sa[192 + u] = h2[id * 64 + u]; }
  __syncthreads();
  float a0 = b0[t];
  for (int k = 0; k < 256; ++k) a0 += sa[k] * W0[k * 128 + t];
  sh[t] = fmaxf(a0, 0.f);
  __syncthreads();
  float a1 = b1[t];
  for (int k = 0; k < 128; ++k) a1 += sh[k] * W1[k * 128 + t];
  sr[t] = fmaxf(a1, 0.f) * W2[t];
  __syncthreads();
  if (t == 0) {
    float s = b2[0];
    for (int k = 0; k < 128; ++k) s += sr[k];
    out[e] = s;
  }
}

extern "C" void kernel_launch(void* const* d_in, const int* in_sizes, int n_in,
                              void* d_out, int out_size, void* d_ws, size_t ws_size,
                              hipStream_t stream) {
  const float* h1 = (const float*)d_in[0];
  const float* h2 = (const float*)d_in[1];
  const int* src = (const int*)d_in[2];
  const int* dst = (const int*)d_in[3];
  const float* W0 = (const float*)d_in[4];
  const float* b0 = (const float*)d_in[5];
  const float* W1 = (const float*)d_in[6];
  const float* b1 = (const float*)d_in[7];
  const float* W2 = (const float*)d_in[8];
  const float* b2 = (const float*)d_in[9];
  float* out = (float*)d_out;

  const int D = 64;
  const int nNodes = in_sizes[0] / D;
  const int E = in_sizes[2];

  char* ws = (char*)d_ws;
  __bf16* W0T = (__bf16*)(ws);             // 65536 B
  __bf16* W1T = (__bf16*)(ws + 65536);     // 32768 B
  __bf16* hb1 = (__bf16*)(ws + 98304);
  const size_t hbBytes = (size_t)nNodes * D * sizeof(__bf16);
  __bf16* hb2 = (__bf16*)(ws + 98304 + hbBytes);
  const bool useBT = ws_size >= 98304 + 2 * hbBytes;

  if (!useBT) {
    edge_mlp_fallback<<<dim3(E), dim3(128), 0, stream>>>(
        h1, h2, src, dst, W0, b0, W1, b1, W2, b2, out, E);
    return;
  }

  cvt_w_kernel<<<dim3(192), dim3(256), 0, stream>>>(W0, W1, W0T, W1T);
  {
    const int n4 = nNodes * D / 4;
    int blocks = (2 * n4 + 255) / 256;
    if (blocks > 2048) blocks = 2048;
    cvt_nodes_kernel<<<dim3(blocks), dim3(256), 0, stream>>>(h1, h2, hb1, hb2, n4);
  }

  const int nTiles = (E + 63) / 64;
  int grid = nTiles < 1024 ? nTiles : 1024;
  edge_mlp_kernel<<<dim3(grid), dim3(256), 0, stream>>>(
      hb1, hb2, src, dst, W0T, b0, W1T, b1, W2, b2, out, E, nTiles);
}

// Round 3
// 188.447 us; speedup vs baseline: 6.0505x; 1.4195x over previous
//
#include <hip/hip_runtime.h>
#include <hip/hip_bf16.h>
#include <stdint.h>

// EdgeMLP: out[e] = relu(relu(concat(h1[src],h1[dst],h2[src],h2[dst]) @ W0 + b0) @ W1 + b1) @ W2 + b2
// Round 3: swapped-operand MFMA (compute D^T = W^T * A^T) so the n-axis lands
// row-wise in the C-layout: vectorized 8B sH writes + cheap layer-2 tail.
// Persistent blocks, register-resident weights (wave N-split), global_load_lds
// gather with both-sides XOR swizzle, double-buffered sA.

typedef __attribute__((ext_vector_type(8))) __bf16 bf16x8;
typedef __attribute__((ext_vector_type(4))) __bf16 bf16x4;
typedef __attribute__((ext_vector_type(4))) float  floatx4;

__device__ inline floatx4 mfma16x16x32(bf16x8 a, bf16x8 b, floatx4 c) {
  return __builtin_amdgcn_mfma_f32_16x16x32_bf16(a, b, c, 0, 0, 0);
}

__device__ inline void bar_lds() {
  asm volatile("s_waitcnt lgkmcnt(0)" ::: "memory");
  __builtin_amdgcn_s_barrier();
}

// ---- prep: f32 -> bf16 node feature tables ----
__global__ void cvt_nodes_kernel(const float* __restrict__ h1,
                                 const float* __restrict__ h2,
                                 __bf16* __restrict__ hb1,
                                 __bf16* __restrict__ hb2, int n4) {
  const int stride = gridDim.x * blockDim.x;
  for (int i = blockIdx.x * blockDim.x + threadIdx.x; i < 2 * n4; i += stride) {
    const bool second = i >= n4;
    const int j = second ? i - n4 : i;
    const float4 v = reinterpret_cast<const float4*>(second ? h2 : h1)[j];
    bf16x4 o;
    o[0] = (__bf16)v.x; o[1] = (__bf16)v.y; o[2] = (__bf16)v.z; o[3] = (__bf16)v.w;
    reinterpret_cast<bf16x4*>(second ? hb2 : hb1)[j] = o;
  }
}

// ---- prep: transpose weights to bf16 [N][K] ----
__global__ void cvt_w_kernel(const float* __restrict__ W0, const float* __restrict__ W1,
                             __bf16* __restrict__ W0T, __bf16* __restrict__ W1T) {
  const int t = blockIdx.x * 256 + threadIdx.x;
  if (t < 128 * 256) {                 // W0T[n][k] = W0[k][n]
    const int n = t >> 8, k = t & 255;
    W0T[t] = (__bf16)W0[k * 128 + n];
  } else {
    const int t2 = t - 128 * 256;      // W1T[n][k] = W1[k][n]
    const int n = t2 >> 7, k = t2 & 127;
    W1T[t2] = (__bf16)W1[k * 128 + n];
  }
}

// ---- main kernel ----
__global__ __launch_bounds__(256, 2)
void edge_mlp_kernel(const __bf16* __restrict__ hb1, const __bf16* __restrict__ hb2,
                     const int* __restrict__ srcI, const int* __restrict__ dstI,
                     const __bf16* __restrict__ W0T, const float* __restrict__ b0,
                     const __bf16* __restrict__ W1T, const float* __restrict__ b1,
                     const float* __restrict__ W2, const float* __restrict__ b2,
                     float* __restrict__ out, int E, int nTiles) {
  // sA: 2 x [64 edges][256 feats] bf16 (double buffer), row stride 512 B.
  // Physical layout linear (global_load_lds); logical 16B chunk c of row e is
  // stored at physical chunk c^(e&7); reads XOR the byte offset with (e&7)<<4.
  // sH: [64][128] bf16, row stride 256 B, same XOR swizzle.
  __shared__ char sA[2 * 64 * 512];
  __shared__ char sH[64 * 256];

  const int tid  = threadIdx.x;
  const int lane = tid & 63;
  const int l15  = lane & 15;
  const int hi   = lane >> 4;
  const int hi16 = hi * 16;
  const int wvU  = __builtin_amdgcn_readfirstlane(tid >> 6);  // wave id (uniform)
  const int wv16 = wvU * 16;
  const int wvByte = wvU * 8192;

  // gather role of this lane
  const int lhalf = lane >> 5;          // which of the 2 edges per issue
  const int sseg  = (lane >> 3) & 3;    // 0=h1[src] 1=h1[dst] 2=h2[src] 3=h2[dst]
  const int* idxTab = (sseg & 1) ? dstI : srcI;
  const __bf16* segBase = (sseg < 2) ? hb1 : hb2;

  // ---- per-wave register-resident weights (N-split: cols [32*wv, 32*wv+32)) ----
  // W0T/W1T rows are [n][k]; a row-slice IS an A-fragment for the swapped MFMA
  // (A-frag: 16-index = lane&15 -> n within nt-block, k = hi*8 + j).
  const int col0 = wvU * 32 + l15;
  const int col1 = col0 + 16;
  bf16x8 w0f[8][2];
  const bf16x8* w0p = reinterpret_cast<const bf16x8*>(W0T);
#pragma unroll
  for (int kk = 0; kk < 8; ++kk) {
    w0f[kk][0] = w0p[col0 * 32 + kk * 4 + hi];
    w0f[kk][1] = w0p[col1 * 32 + kk * 4 + hi];
  }
  bf16x8 w1f[4][2];
  const bf16x8* w1p = reinterpret_cast<const bf16x8*>(W1T);
#pragma unroll
  for (int kk = 0; kk < 4; ++kk) {
    w1f[kk][0] = w1p[col0 * 16 + kk * 4 + hi];
    w1f[kk][1] = w1p[col1 * 16 + kk * 4 + hi];
  }
  // per-lane n-constants for the transposed C-layout: n = wv*32 + nt*16 + hi*4 + r
  float b0c[2][4], b1c[2][4], w2c[2][4];
#pragma unroll
  for (int nt = 0; nt < 2; ++nt) {
#pragma unroll
    for (int r = 0; r < 4; ++r) {
      const int n = wvU * 32 + nt * 16 + hi * 4 + r;
      b0c[nt][r] = b0[n];
      b1c[nt][r] = b1[n];
      w2c[nt][r] = W2[n];
    }
  }
  const float b2v = b2[0];

  const int tstride = gridDim.x;

  auto loadIdx = [&](int (&dst8)[8], int tt2) {
    const bool valid = tt2 < nTiles;
#pragma unroll
    for (int i = 0; i < 8; ++i) {
      const int eLoc = wv16 + i * 2 + lhalf;
      const int ge = tt2 * 64 + eLoc;
      dst8[i] = (valid && ge < E) ? idxTab[ge] : 0;
    }
  };

  auto issueGather = [&](int nb, const int (&idx8)[8]) {
#pragma unroll
    for (int i = 0; i < 8; ++i) {
      const int eLoc = wv16 + i * 2 + lhalf;
      const int c = (lane & 7) ^ (eLoc & 7);
      const __bf16* g = segBase + (size_t)idx8[i] * 64 + c * 8;
      char* l = sA + nb * 32768 + wvByte + i * 1024;  // + lane*16 added by HW
      __builtin_amdgcn_global_load_lds(
          (const __attribute__((address_space(1))) void*)g,
          (__attribute__((address_space(3))) void*)l, 16, 0, 0);
    }
  };

  // ---- prologue ----
  int tile0 = blockIdx.x;
  int idxA[8], idxB[8];
  loadIdx(idxA, tile0);
  issueGather(0, idxA);                 // gathers for first tile -> buf0
  loadIdx(idxB, tile0 + tstride);       // indices for tile+1
  int cur = 0;

  for (int tt = tile0; tt < nTiles; tt += tstride) {
    __syncthreads();  // drains vmcnt: buf[cur] ready; orders sH/sRed reuse

    // prefetch next tile's gathers and next-next indices
    if (tt + tstride < nTiles) issueGather(cur ^ 1, idxB);
    loadIdx(idxA, tt + 2 * tstride);

    const char* sAc = sA + cur * 32768;

    // ---- layer 0 (swapped): accT[nt][mt] col=edge, row=n ----
    floatx4 accT[4][2];
#pragma unroll
    for (int mt = 0; mt < 4; ++mt) { accT[mt][0] = (floatx4)0.f; accT[mt][1] = (floatx4)0.f; }
#pragma unroll
    for (int kk = 0; kk < 8; ++kk) {
#pragma unroll
      for (int mt = 0; mt < 4; ++mt) {
        const int row = mt * 16 + l15;   // edge within tile (B-frag col)
        const bf16x8 a = *reinterpret_cast<const bf16x8*>(
            sAc + row * 512 + ((kk * 64 + hi16) ^ ((row & 7) << 4)));
        accT[mt][0] = mfma16x16x32(w0f[kk][0], a, accT[mt][0]);
        accT[mt][1] = mfma16x16x32(w0f[kk][1], a, accT[mt][1]);
      }
    }

    // bias + relu -> sH: lane holds 4 contiguous n for edge mt*16+l15 -> 8B writes
#pragma unroll
    for (int mt = 0; mt < 4; ++mt) {
      const int e = mt * 16 + l15;
      char* rowp = sH + e * 256;
      const int swz = (e & 7) << 4;
#pragma unroll
      for (int nt = 0; nt < 2; ++nt) {
        bf16x4 pk;
#pragma unroll
        for (int r = 0; r < 4; ++r)
          pk[r] = (__bf16)fmaxf(accT[mt][nt][r] + b0c[nt][r], 0.0f);
        const int nb = wvU * 64 + nt * 32 + hi * 8;  // byte offset of n0 within row
        *reinterpret_cast<bf16x4*>(rowp + (nb ^ swz)) = pk;
      }
    }
    bar_lds();  // B2: sH visible

    // ---- layer 1 (swapped): acc2T[mt][nt] col=edge, row=n ----
    floatx4 acc2T[4][2];
#pragma unroll
    for (int mt = 0; mt < 4; ++mt) { acc2T[mt][0] = (floatx4)0.f; acc2T[mt][1] = (floatx4)0.f; }
#pragma unroll
    for (int kk = 0; kk < 4; ++kk) {
#pragma unroll
      for (int mt = 0; mt < 4; ++mt) {
        const int row = mt * 16 + l15;
        const bf16x8 a = *reinterpret_cast<const bf16x8*>(
            sH + row * 256 + ((kk * 64 + hi16) ^ ((row & 7) << 4)));
        acc2T[mt][0] = mfma16x16x32(w1f[kk][0], a, acc2T[mt][0]);
        acc2T[mt][1] = mfma16x16x32(w1f[kk][1], a, acc2T[mt][1]);
      }
    }

    // ---- layer 2: per-lane dot over 8 n-values, reduce across hi-groups ----
    float* sRedF = (float*)sAc;  // overlay on consumed sA[cur]
#pragma unroll
    for (int mt = 0; mt < 4; ++mt) {
      float p = 0.f;
#pragma unroll
      for (int nt = 0; nt < 2; ++nt)
#pragma unroll
        for (int r = 0; r < 4; ++r)
          p += fmaxf(acc2T[mt][nt][r] + b1c[nt][r], 0.0f) * w2c[nt][r];
      p += __shfl_xor(p, 16);
      p += __shfl_xor(p, 32);
      if (lane < 16) sRedF[wvU * 64 + mt * 16 + l15] = p;
    }
    bar_lds();  // B3: partials visible

    if (tid < 64) {
      const int ge = tt * 64 + tid;
      if (ge < E) {
        out[ge] = sRedF[tid] + sRedF[64 + tid] + sRedF[128 + tid] +
                  sRedF[192 + tid] + b2v;
      }
    }

    // rotate prefetched indices
#pragma unroll
    for (int i = 0; i < 8; ++i) idxB[i] = idxA[i];
    cur ^= 1;
  }
}

// ---- correctness fallback (only if workspace too small for bf16 tables) ----
__global__ void edge_mlp_fallback(const float* __restrict__ h1, const float* __restrict__ h2,
                                  const int* __restrict__ src, const int* __restrict__ dst,
                                  const float* __restrict__ W0, const float* __restrict__ b0,
                                  const float* __restrict__ W1, const float* __restrict__ b1,
                                  const float* __restrict__ W2, const float* __restrict__ b2,
                                  float* __restrict__ out, int E) {
  __shared__ float sa[256];
  __shared__ float sh[128];
  __shared__ float sr[128];
  const int e = blockIdx.x;
  if (e >= E) return;
  const int t = threadIdx.x;  // 128 threads
  const int is = src[e], id = dst[e];
  if (t < 64) { sa[t] = h1[is * 64 + t]; sa[128 + t] = h2[is * 64 + t]; }
  else { const int u = t - 64; sa[64 + u] = h1[id * 64 + u]; sa[192 + u] = h2[id * 64 + u]; }
  __syncthreads();
  float a0 = b0[t];
  for (int k = 0; k < 256; ++k) a0 += sa[k] * W0[k * 128 + t];
  sh[t] = fmaxf(a0, 0.f);
  __syncthreads();
  float a1 = b1[t];
  for (int k = 0; k < 128; ++k) a1 += sh[k] * W1[k * 128 + t];
  sr[t] = fmaxf(a1, 0.f) * W2[t];
  __syncthreads();
  if (t == 0) {
    float s = b2[0];
    for (int k = 0; k < 128; ++k) s += sr[k];
    out[e] = s;
  }
}

extern "C" void kernel_launch(void* const* d_in, const int* in_sizes, int n_in,
                              void* d_out, int out_size, void* d_ws, size_t ws_size,
                              hipStream_t stream) {
  const float* h1 = (const float*)d_in[0];
  const float* h2 = (const float*)d_in[1];
  const int* src = (const int*)d_in[2];
  const int* dst = (const int*)d_in[3];
  const float* W0 = (const float*)d_in[4];
  const float* b0 = (const float*)d_in[5];
  const float* W1 = (const float*)d_in[6];
  const float* b1 = (const float*)d_in[7];
  const float* W2 = (const float*)d_in[8];
  const float* b2 = (const float*)d_in[9];
  float* out = (float*)d_out;

  const int D = 64;
  const int nNodes = in_sizes[0] / D;
  const int E = in_sizes[2];

  char* ws = (char*)d_ws;
  __bf16* W0T = (__bf16*)(ws);             // 65536 B
  __bf16* W1T = (__bf16*)(ws + 65536);     // 32768 B
  __bf16* hb1 = (__bf16*)(ws + 98304);
  const size_t hbBytes = (size_t)nNodes * D * sizeof(__bf16);
  __bf16* hb2 = (__bf16*)(ws + 98304 + hbBytes);
  const bool useBT = ws_size >= 98304 + 2 * hbBytes;

  if (!useBT) {
    edge_mlp_fallback<<<dim3(E), dim3(128), 0, stream>>>(
        h1, h2, src, dst, W0, b0, W1, b1, W2, b2, out, E);
    return;
  }

  cvt_w_kernel<<<dim3(192), dim3(256), 0, stream>>>(W0, W1, W0T, W1T);
  {
    const int n4 = nNodes * D / 4;
    int blocks = (2 * n4 + 255) / 256;
    if (blocks > 2048) blocks = 2048;
    cvt_nodes_kernel<<<dim3(blocks), dim3(256), 0, stream>>>(h1, h2, hb1, hb2, n4);
  }

  const int nTiles = (E + 63) / 64;
  int grid = nTiles < 1024 ? nTiles : 1024;
  edge_mlp_kernel<<<dim3(grid), dim3(256), 0, stream>>>(
      hb1, hb2, src, dst, W0T, b0, W1T, b1, W2, b2, out, E, nTiles);
}